// Round 1
// baseline (7656.416 us; speedup 1.0000x reference)
//
#include <hip/hip_runtime.h>
#include <hip/hip_bf16.h>

#define HH 128
#define WW 128
#define BB 4
#define EPSV 1e-5f

// ---------------------------------------------------------------------------
// conv3x3 (pad=1, stride=1) + BN (+optional ReLU), optional summed dual input.
// Block: one (b, h) row x 64 output channels. 256 threads.
// Thread: 4 output channels x 8 consecutive w. LDS-staged inputs (zero halo)
// and weights, 8 input channels per chunk.
// ---------------------------------------------------------------------------
#define LOAD16(dst, ptr) do { \
  const float4 q0 = *(const float4*)((ptr)+0); \
  const float4 q1 = *(const float4*)((ptr)+4); \
  const float4 q2 = *(const float4*)((ptr)+8); \
  const float4 q3 = *(const float4*)((ptr)+12); \
  dst[0]=q0.x; dst[1]=q0.y; dst[2]=q0.z; dst[3]=q0.w; \
  dst[4]=q1.x; dst[5]=q1.y; dst[6]=q1.z; dst[7]=q1.w; \
  dst[8]=q2.x; dst[9]=q2.y; dst[10]=q2.z; dst[11]=q2.w; \
  dst[12]=q3.x; dst[13]=q3.y; dst[14]=q3.z; dst[15]=q3.w; \
} while(0)

template<bool SUM2, bool RELU>
__global__ __launch_bounds__(256) void conv3x3_bn(
    const float* __restrict__ in1, const float* __restrict__ in2,
    const float* __restrict__ wgt,
    const float* __restrict__ gg, const float* __restrict__ bbp,
    const float* __restrict__ mmp, const float* __restrict__ vvp,
    float* __restrict__ out, int CIN, int COUT)
{
  const int o_base = blockIdx.x * 64;
  const int h  = blockIdx.y;
  const int b  = blockIdx.z;
  const int tid = threadIdx.x;

  __shared__ float inbuf[8][3][136];   // [ic][row][4 halo + 128 + 4 pad]
  __shared__ float wbuf[8][64][12];    // [ic][oc][9 taps + 3 pad]

  const int g    = tid & 15;    // w-group
  const int w8   = g * 8;
  const int ogrp = tid >> 4;    // 0..15

  float acc[4][8];
  #pragma unroll
  for (int r = 0; r < 4; ++r)
    #pragma unroll
    for (int j = 0; j < 8; ++j) acc[r][j] = 0.f;

  const int nchunk = CIN >> 3;
  for (int ch = 0; ch < nchunk; ++ch) {
    const int i0 = ch * 8;
    __syncthreads();
    // stage input rows (h-1, h, h+1) for 8 input channels, zero halo
    for (int idx = tid; idx < 8 * 3 * 136; idx += 256) {
      const int ii  = idx / (3 * 136);
      const int rem = idx % (3 * 136);
      const int r   = rem / 136;
      const int c   = rem % 136;
      const int hr  = h + r - 1;
      float val = 0.f;
      if (c >= 4 && c < 132 && hr >= 0 && hr < HH) {
        const size_t off = ((size_t)(b * CIN + i0 + ii) * HH + hr) * WW + (c - 4);
        val = in1[off];
        if (SUM2) val += in2[off];
      }
      inbuf[ii][r][c] = val;
    }
    // stage weights
    for (int idx = tid; idx < 8 * 64 * 9; idx += 256) {
      const int ii  = idx / 576;
      const int rem = idx % 576;
      const int oo  = rem / 9;
      const int tap = rem % 9;
      wbuf[ii][oo][tap] = wgt[((size_t)(o_base + oo) * CIN + (i0 + ii)) * 9 + tap];
    }
    __syncthreads();

    #pragma unroll
    for (int ii = 0; ii < 8; ++ii) {
      float v0[16], v1[16], v2[16];
      LOAD16(v0, &inbuf[ii][0][w8]);
      LOAD16(v1, &inbuf[ii][1][w8]);
      LOAD16(v2, &inbuf[ii][2][w8]);
      #pragma unroll
      for (int rr = 0; rr < 4; ++rr) {
        const float* wp = &wbuf[ii][ogrp * 4 + rr][0];
        const float4 wa = *(const float4*)(wp);
        const float4 wb = *(const float4*)(wp + 4);
        const float wt0 = wa.x, wt1 = wa.y, wt2 = wa.z;
        const float wt3 = wa.w, wt4 = wb.x, wt5 = wb.y;
        const float wt6 = wb.z, wt7 = wb.w, wt8 = wp[8];
        #pragma unroll
        for (int j = 0; j < 8; ++j) {
          float s = acc[rr][j];
          s = fmaf(v0[3 + j], wt0, s);
          s = fmaf(v0[4 + j], wt1, s);
          s = fmaf(v0[5 + j], wt2, s);
          s = fmaf(v1[3 + j], wt3, s);
          s = fmaf(v1[4 + j], wt4, s);
          s = fmaf(v1[5 + j], wt5, s);
          s = fmaf(v2[3 + j], wt6, s);
          s = fmaf(v2[4 + j], wt7, s);
          s = fmaf(v2[5 + j], wt8, s);
          acc[rr][j] = s;
        }
      }
    }
  }

  // epilogue: BN (+ReLU), vectorized store
  #pragma unroll
  for (int rr = 0; rr < 4; ++rr) {
    const int o = o_base + ogrp * 4 + rr;
    const float sc = gg[o] * rsqrtf(vvp[o] + EPSV);
    const float tb = bbp[o] - mmp[o] * sc;
    float res[8];
    #pragma unroll
    for (int j = 0; j < 8; ++j) {
      float v = acc[rr][j] * sc + tb;
      if (RELU) v = fmaxf(v, 0.f);
      res[j] = v;
    }
    float* op = out + (((size_t)b * COUT + o) * HH + h) * WW + w8;
    float4 r0, r1;
    r0.x = res[0]; r0.y = res[1]; r0.z = res[2]; r0.w = res[3];
    r1.x = res[4]; r1.y = res[5]; r1.z = res[6]; r1.w = res[7];
    *(float4*)(op)     = r0;
    *(float4*)(op + 4) = r1;
  }
}

// ---------------------------------------------------------------------------
// 1x1 conv (256->256) + BN, fused add with existing buffer + ReLU, in place.
// Block: one (b,h) row x 128 output channels. Thread: 8 o x 8 w.
// ---------------------------------------------------------------------------
__global__ __launch_bounds__(256) void conv1x1_add_relu(
    const float* __restrict__ x, const float* __restrict__ wgt,
    const float* __restrict__ gg, const float* __restrict__ bbp,
    const float* __restrict__ mmp, const float* __restrict__ vvp,
    float* __restrict__ inout)
{
  const int o_base = blockIdx.x * 128;
  const int h  = blockIdx.y;
  const int b  = blockIdx.z;
  const int tid = threadIdx.x;

  __shared__ float inbuf[32][128];
  __shared__ float wbuf[32][132];   // padded to keep f4 alignment, spread banks

  const int g    = tid & 15;
  const int w8   = g * 8;
  const int ogrp = tid >> 4;   // 0..15, each owns 8 consecutive o

  float acc[8][8];
  #pragma unroll
  for (int r = 0; r < 8; ++r)
    #pragma unroll
    for (int j = 0; j < 8; ++j) acc[r][j] = 0.f;

  for (int ch = 0; ch < 256 / 32; ++ch) {
    const int i0 = ch * 32;
    __syncthreads();
    for (int idx = tid; idx < 32 * 128; idx += 256) {
      const int ii = idx >> 7;
      const int c  = idx & 127;
      inbuf[ii][c] = x[((size_t)(b * 256 + i0 + ii) * HH + h) * WW + c];
    }
    for (int idx = tid; idx < 128 * 32; idx += 256) {
      const int oo = idx >> 5;
      const int ii = idx & 31;
      wbuf[ii][oo] = wgt[(size_t)(o_base + oo) * 256 + (i0 + ii)];
    }
    __syncthreads();

    #pragma unroll
    for (int ii = 0; ii < 32; ++ii) {
      const float4 a0 = *(const float4*)(&inbuf[ii][w8]);
      const float4 a1 = *(const float4*)(&inbuf[ii][w8 + 4]);
      const float4 wa = *(const float4*)(&wbuf[ii][ogrp * 8]);
      const float4 wb = *(const float4*)(&wbuf[ii][ogrp * 8 + 4]);
      const float av[8] = {a0.x, a0.y, a0.z, a0.w, a1.x, a1.y, a1.z, a1.w};
      const float wv[8] = {wa.x, wa.y, wa.z, wa.w, wb.x, wb.y, wb.z, wb.w};
      #pragma unroll
      for (int rr = 0; rr < 8; ++rr)
        #pragma unroll
        for (int j = 0; j < 8; ++j)
          acc[rr][j] = fmaf(av[j], wv[rr], acc[rr][j]);
    }
  }

  #pragma unroll
  for (int rr = 0; rr < 8; ++rr) {
    const int o = o_base + ogrp * 8 + rr;
    const float sc = gg[o] * rsqrtf(vvp[o] + EPSV);
    const float tb = bbp[o] - mmp[o] * sc;
    float* op = inout + (((size_t)b * 256 + o) * HH + h) * WW + w8;
    float4 p0 = *(const float4*)(op);
    float4 p1 = *(const float4*)(op + 4);
    float res[8] = {p0.x, p0.y, p0.z, p0.w, p1.x, p1.y, p1.z, p1.w};
    #pragma unroll
    for (int j = 0; j < 8; ++j)
      res[j] = fmaxf(res[j] + acc[rr][j] * sc + tb, 0.f);
    float4 r0, r1;
    r0.x = res[0]; r0.y = res[1]; r0.z = res[2]; r0.w = res[3];
    r1.x = res[4]; r1.y = res[5]; r1.z = res[6]; r1.w = res[7];
    *(float4*)(op)     = r0;
    *(float4*)(op + 4) = r1;
  }
}

// ---------------------------------------------------------------------------
// reverse cummax along H, in place. One block per (b,c) plane, thread per w.
// ---------------------------------------------------------------------------
__global__ __launch_bounds__(128) void scan_h_rev(float* __restrict__ p)
{
  const int bc = blockIdx.x;           // b*128 + c
  const int w  = threadIdx.x;
  float* base = p + (size_t)bc * HH * WW + w;
  float cur = base[(HH - 1) * WW];
  for (int hr = HH - 2; hr >= 0; --hr) {
    cur = fmaxf(cur, base[hr * WW]);
    base[hr * WW] = cur;
  }
}

// ---------------------------------------------------------------------------
// reverse cummax along W, in place. One thread per (b,c,h) row.
// ---------------------------------------------------------------------------
__global__ __launch_bounds__(256) void scan_w_rev(float* __restrict__ p)
{
  const int id = blockIdx.x * 256 + threadIdx.x;  // (b*128 + c)*128 + h
  float* row = p + (size_t)id * WW;
  float cur = row[WW - 1];
  for (int w = WW - 2; w >= 0; --w) {
    cur = fmaxf(cur, row[w]);
    row[w] = cur;
  }
}

extern "C" void kernel_launch(void* const* d_in, const int* in_sizes, int n_in,
                              void* d_out, int out_size, void* d_ws, size_t ws_size,
                              hipStream_t stream) {
  const float* x    = (const float*)d_in[0];
  const float* w_p1 = (const float*)d_in[1];
  const float* g_p1 = (const float*)d_in[2];
  const float* b_p1 = (const float*)d_in[3];
  const float* m_p1 = (const float*)d_in[4];
  const float* v_p1 = (const float*)d_in[5];
  const float* w_p2 = (const float*)d_in[6];
  const float* g_p2 = (const float*)d_in[7];
  const float* b_p2 = (const float*)d_in[8];
  const float* m_p2 = (const float*)d_in[9];
  const float* v_p2 = (const float*)d_in[10];
  const float* w_pc = (const float*)d_in[11];
  const float* g_pb = (const float*)d_in[12];
  const float* b_pb = (const float*)d_in[13];
  const float* m_pb = (const float*)d_in[14];
  const float* v_pb = (const float*)d_in[15];
  const float* w_c1 = (const float*)d_in[16];
  const float* g_b1 = (const float*)d_in[17];
  const float* b_b1 = (const float*)d_in[18];
  const float* m_b1 = (const float*)d_in[19];
  const float* v_b1 = (const float*)d_in[20];
  const float* w_c2 = (const float*)d_in[21];
  const float* g_c2 = (const float*)d_in[22];
  const float* b_c2 = (const float*)d_in[23];
  const float* m_c2 = (const float*)d_in[24];
  const float* v_c2 = (const float*)d_in[25];

  float* out = (float*)d_out;

  // workspace layout (floats): p1 [4,128,128,128], p2 [same], pb [4,256,128,128]
  const size_t P_ELEMS = (size_t)BB * 128 * HH * WW;   // 8M floats = 32MB
  float* p1 = (float*)d_ws;
  float* p2 = p1 + P_ELEMS;
  float* pb = p2 + P_ELEMS;                             // 16M floats = 64MB

  // p1 = relu(bn(conv3x3(x, w_p1)))
  conv3x3_bn<false, true><<<dim3(2, HH, BB), 256, 0, stream>>>(
      x, nullptr, w_p1, g_p1, b_p1, m_p1, v_p1, p1, 256, 128);
  // p2 = relu(bn(conv3x3(x, w_p2)))
  conv3x3_bn<false, true><<<dim3(2, HH, BB), 256, 0, stream>>>(
      x, nullptr, w_p2, g_p2, b_p2, m_p2, v_p2, p2, 256, 128);
  // top pool: reverse cummax over H (in place on p1)
  scan_h_rev<<<dim3(BB * 128), 128, 0, stream>>>(p1);
  // left pool: reverse cummax over W (in place on p2)
  scan_w_rev<<<dim3(BB * 128 * HH / 256), 256, 0, stream>>>(p2);
  // pb = bn(conv3x3(p1 + p2, w_pc))   (no relu)
  conv3x3_bn<true, false><<<dim3(4, HH, BB), 256, 0, stream>>>(
      p1, p2, w_pc, g_pb, b_pb, m_pb, v_pb, pb, 128, 256);
  // pb = relu(pb + bn(conv1x1(x, w_c1)))   (in place)
  conv1x1_add_relu<<<dim3(2, HH, BB), 256, 0, stream>>>(
      x, w_c1, g_b1, b_b1, m_b1, v_b1, pb);
  // out = relu(bn(conv3x3(pb, w_c2)))
  conv3x3_bn<false, true><<<dim3(4, HH, BB), 256, 0, stream>>>(
      pb, nullptr, w_c2, g_c2, b_c2, m_c2, v_c2, out, 256, 256);
}

// Round 2
// 340.901 us; speedup vs baseline: 22.4594x; 22.4594x over previous
//
#include <hip/hip_runtime.h>
#include <hip/hip_bf16.h>

#define HH 128
#define WW 128
#define BB 4
#define NPIX 16384            // HH*WW
#define EPSV 1e-5f

using bfrag = __attribute__((ext_vector_type(8))) short;     // 8 bf16 (4 VGPRs)
using f32x4 = __attribute__((ext_vector_type(4))) float;
using us8   = __attribute__((ext_vector_type(8))) unsigned short;

__device__ __forceinline__ float bf2f(ushort u) {
  union { unsigned int i; float f; } x; x.i = ((unsigned int)u) << 16; return x.f;
}
__device__ __forceinline__ ushort f2bf(float f) {
  union { float f; unsigned int i; } x; x.f = f;
  unsigned int r = x.i + 0x7fffu + ((x.i >> 16) & 1u);   // RNE
  return (ushort)(r >> 16);
}

#define GLOAD16(gsrc, ldst) \
  __builtin_amdgcn_global_load_lds( \
      (const __attribute__((address_space(1))) unsigned int*)(gsrc), \
      (__attribute__((address_space(3))) unsigned int*)(ldst), 16, 0, 0)

// ---------------------------------------------------------------------------
// Implicit-GEMM conv via MFMA.  C[o][p] = sum_k W'[o][k] * X'[k][p].
// Block: 128 outs x 128 pixels (one image row h), 4 waves, wave = 64x64.
// A (weights) pre-repacked in global to the exact swizzled LDS image -> linear
// global_load_lds.  B (xT rows) staged with inverse-swizzled per-lane source.
// EPI: 0 = relu->bf16 NCHW, 1 = bf16 NCHW (no relu), 2 = +addsrc,relu->bf16,
//      3 = relu->fp32 NCHW (final output).
// ---------------------------------------------------------------------------
template<int CIN, int COUT, int TAPS, int EPI>
__global__ __launch_bounds__(256)
void convgemm(const ushort* __restrict__ Bsrc,   // [b][16384][CIN] bf16
              const ushort* __restrict__ wR,     // repacked weights
              const float*  __restrict__ tb,     // bias per out-channel
              const ushort* __restrict__ addsrc, // EPI==2: bf16 NCHW to add
              void*          __restrict__ outp,
              const ushort* __restrict__ zerop)  // 256B of zeros
{
  __shared__ ushort lds[16384];                  // 16KB A | 16KB B
  const int h      = blockIdx.x;
  const int o_base = blockIdx.y * 128;
  const int b      = blockIdx.z;
  const int tid  = threadIdx.x;
  const int lane = tid & 63;
  const int wid  = tid >> 6;
  const int m0 = (wid >> 1) * 64;
  const int n0 = (wid & 1) * 64;
  constexpr int nch = CIN / 64;

  f32x4 acc[4][4];
  #pragma unroll
  for (int i = 0; i < 4; ++i)
    #pragma unroll
    for (int j = 0; j < 4; ++j) acc[i][j] = (f32x4){0.f, 0.f, 0.f, 0.f};

  // staging lane constants (B side): per segment, LDS row & unswizzled slot
  int rowB[4], rowoff[4];
  #pragma unroll
  for (int s = 0; s < 4; ++s) {
    const int boff = (wid * 4 + s) * 1024 + lane * 16;   // byte off in B image
    rowB[s] = boff >> 7;                                  // pixel row 0..127
    const int slot = ((boff >> 4) & 7) ^ (rowB[s] & 7);   // unswizzled k-slot
    rowoff[s] = rowB[s] * CIN + slot * 8;                 // element offset
  }
  const size_t Bbase = (size_t)b * NPIX * CIN;

  for (int tap = 0; tap < TAPS; ++tap) {
    const int dy = (TAPS == 9) ? tap / 3 - 1 : 0;
    const int dx = (TAPS == 9) ? tap % 3 - 1 : 0;
    const int hy = h + dy;
    if (hy < 0 || hy >= HH) continue;                     // uniform per block
    const int zr = (dx < 0) ? 0 : ((dx > 0) ? 127 : -1);  // zero-padded row
    const int pb = hy * WW + dx;

    for (int ch = 0; ch < nch; ++ch) {
      __syncthreads();
      const ushort* wsrc = wR + (((size_t)((tap * nch + ch) * COUT) + o_base) << 6);
      const ushort* bch  = Bsrc + Bbase + (size_t)pb * CIN + ch * 64;
      #pragma unroll
      for (int s = 0; s < 4; ++s) {
        const int off = (wid * 4 + s) * 1024;             // bytes
        GLOAD16((const char*)wsrc + off + lane * 16, (char*)lds + off);
        const ushort* bsrc = (rowB[s] == zr) ? zerop : (bch + rowoff[s]);
        GLOAD16(bsrc, (char*)lds + 16384 + off);
      }
      __syncthreads();

      #pragma unroll
      for (int kc = 0; kc < 2; ++kc) {
        const int sw = ((((kc << 2) | (lane >> 4)) ^ (lane & 7)) << 4); // bytes
        bfrag af[4], bfv[4];
        #pragma unroll
        for (int mf = 0; mf < 4; ++mf)
          af[mf] = *(const bfrag*)((const char*)lds + (m0 + mf * 16 + (lane & 15)) * 128 + sw);
        #pragma unroll
        for (int nf = 0; nf < 4; ++nf)
          bfv[nf] = *(const bfrag*)((const char*)lds + 16384 + (n0 + nf * 16 + (lane & 15)) * 128 + sw);
        #pragma unroll
        for (int mf = 0; mf < 4; ++mf)
          #pragma unroll
          for (int nf = 0; nf < 4; ++nf)
            acc[mf][nf] = __builtin_amdgcn_mfma_f32_16x16x32_bf16(
                af[mf], bfv[nf], acc[mf][nf], 0, 0, 0);
      }
    }
  }

  // epilogue: C row = o (coalesced over p within 16-lane groups)
  const int pc0 = h * WW + n0 + (lane & 15);
  #pragma unroll
  for (int mf = 0; mf < 4; ++mf) {
    #pragma unroll
    for (int r = 0; r < 4; ++r) {
      const int o = o_base + m0 + mf * 16 + (lane >> 4) * 4 + r;
      const float bias = tb[o];
      #pragma unroll
      for (int nf = 0; nf < 4; ++nf) {
        const int p = pc0 + nf * 16;
        float v = acc[mf][nf][r] + bias;
        const size_t oi = (((size_t)(b * COUT + o)) << 14) + p;
        if (EPI == 0)      { v = fmaxf(v, 0.f); ((ushort*)outp)[oi] = f2bf(v); }
        else if (EPI == 1) { ((ushort*)outp)[oi] = f2bf(v); }
        else if (EPI == 2) { v += bf2f(addsrc[oi]); v = fmaxf(v, 0.f);
                             ((ushort*)outp)[oi] = f2bf(v); }
        else               { v = fmaxf(v, 0.f); ((float*)outp)[oi] = v; }
      }
    }
  }
}

// ---------------------------------------------------------------------------
// weight repack: fold BN scale, bf16, swizzled LDS-image layout; emit tb.
// W is OIHW flat [COUT][CIN][TAPS].
// ---------------------------------------------------------------------------
__global__ __launch_bounds__(256)
void wrepack(const float* __restrict__ W, const float* __restrict__ g,
             const float* __restrict__ bb, const float* __restrict__ mm,
             const float* __restrict__ vv, ushort* __restrict__ wR,
             float* __restrict__ tb, int CIN, int COUT, int TAPS)
{
  const int id = blockIdx.x * 256 + threadIdx.x;
  const int total = COUT * CIN * TAPS;
  if (id >= total) return;
  const int tap = id % TAPS;
  const int ci  = (id / TAPS) % CIN;
  const int o   = id / (TAPS * CIN);
  const float sc = g[o] * rsqrtf(vv[o] + EPSV);
  const int nch = CIN / 64;
  const int ch = ci >> 6, kl = ci & 63;
  const int slot = (kl >> 3) ^ (o & 7);
  wR[(((size_t)(tap * nch + ch) * COUT + o) << 6) + (slot << 3) + (kl & 7)] =
      f2bf(W[id] * sc);
  if (ci == 0 && tap == 0) tb[o] = bb[o] - mm[o] * sc;
}

// ---------------------------------------------------------------------------
// x (fp32 NCHW) -> xT (bf16 [b][p][256])
// ---------------------------------------------------------------------------
__global__ __launch_bounds__(256)
void repack_x(const float* __restrict__ x, ushort* __restrict__ xT)
{
  const int b = blockIdx.z;
  const int p = blockIdx.x * 256 + threadIdx.x;
  const size_t xb = (size_t)b * 256 * NPIX;
  ushort* orow = xT + ((size_t)b * NPIX + p) * 256;
  for (int c0 = 0; c0 < 256; c0 += 8) {
    us8 v;
    #pragma unroll
    for (int j = 0; j < 8; ++j)
      v[j] = f2bf(x[xb + (size_t)(c0 + j) * NPIX + p]);
    *(us8*)(orow + c0) = v;
  }
}

// relu1 (bf16 NCHW) -> relu1T (bf16 [b][p][256])  — pure transpose
__global__ __launch_bounds__(256)
void repack_relu1(const ushort* __restrict__ r1, ushort* __restrict__ rT)
{
  const int b = blockIdx.z;
  const int p = blockIdx.x * 256 + threadIdx.x;
  const size_t rb = (size_t)b * 256 * NPIX;
  ushort* orow = rT + ((size_t)b * NPIX + p) * 256;
  for (int c0 = 0; c0 < 256; c0 += 8) {
    us8 v;
    #pragma unroll
    for (int j = 0; j < 8; ++j)
      v[j] = r1[rb + (size_t)(c0 + j) * NPIX + p];
    *(us8*)(orow + c0) = v;
  }
}

// top+left (bf16 NCHW, post-scan) -> sumT (bf16 [b][p][128])
__global__ __launch_bounds__(256)
void sum_repack(const ushort* __restrict__ p1, const ushort* __restrict__ p2,
                ushort* __restrict__ sT)
{
  const int b = blockIdx.z;
  const int p = blockIdx.x * 256 + threadIdx.x;
  const size_t pb = (size_t)b * 128 * NPIX;
  ushort* orow = sT + ((size_t)b * NPIX + p) * 128;
  for (int c0 = 0; c0 < 128; c0 += 8) {
    us8 v;
    #pragma unroll
    for (int j = 0; j < 8; ++j) {
      const size_t oi = pb + (size_t)(c0 + j) * NPIX + p;
      v[j] = f2bf(bf2f(p1[oi]) + bf2f(p2[oi]));
    }
    *(us8*)(orow + c0) = v;
  }
}

// reverse cummax along H, in place, bf16 NCHW. block per (b,c), thread per w.
__global__ __launch_bounds__(128)
void scan_h_rev(ushort* __restrict__ p)
{
  const int bc = blockIdx.x;
  const int w  = threadIdx.x;
  ushort* base = p + (size_t)bc * NPIX + w;
  float cur = bf2f(base[(HH - 1) * WW]);
  for (int hr = HH - 2; hr >= 0; --hr) {
    cur = fmaxf(cur, bf2f(base[hr * WW]));
    base[hr * WW] = f2bf(cur);
  }
}

// reverse cummax along W, in place, bf16. one wave per row, shfl suffix-scan.
__global__ __launch_bounds__(256)
void scan_w_rev(ushort* __restrict__ p)
{
  const int lane = threadIdx.x & 63;
  const int row  = blockIdx.x * 4 + (threadIdx.x >> 6);   // (b*128+c)*128+h
  ushort* r = p + (size_t)row * WW;
  const ushort2 u = ((const ushort2*)r)[lane];
  const float e0 = bf2f(u.x), e1 = bf2f(u.y);
  float m = fmaxf(e0, e1);
  #pragma unroll
  for (int off = 1; off < 64; off <<= 1) {
    const float o = __shfl_down(m, off, 64);
    if (lane + off < 64) m = fmaxf(m, o);
  }
  float s = __shfl_down(m, 1, 64);
  if (lane == 63) s = -3.4e38f;
  const float o1 = fmaxf(e1, s);
  const float o0 = fmaxf(e0, o1);
  ushort2 w; w.x = f2bf(o0); w.y = f2bf(o1);
  ((ushort2*)r)[lane] = w;
}

// ---------------------------------------------------------------------------
extern "C" void kernel_launch(void* const* d_in, const int* in_sizes, int n_in,
                              void* d_out, int out_size, void* d_ws, size_t ws_size,
                              hipStream_t stream) {
  const float* x    = (const float*)d_in[0];
  const float* w_p1 = (const float*)d_in[1];
  const float* g_p1 = (const float*)d_in[2];
  const float* b_p1 = (const float*)d_in[3];
  const float* m_p1 = (const float*)d_in[4];
  const float* v_p1 = (const float*)d_in[5];
  const float* w_p2 = (const float*)d_in[6];
  const float* g_p2 = (const float*)d_in[7];
  const float* b_p2 = (const float*)d_in[8];
  const float* m_p2 = (const float*)d_in[9];
  const float* v_p2 = (const float*)d_in[10];
  const float* w_pc = (const float*)d_in[11];
  const float* g_pb = (const float*)d_in[12];
  const float* b_pb = (const float*)d_in[13];
  const float* m_pb = (const float*)d_in[14];
  const float* v_pb = (const float*)d_in[15];
  const float* w_c1 = (const float*)d_in[16];
  const float* g_b1 = (const float*)d_in[17];
  const float* b_b1 = (const float*)d_in[18];
  const float* m_b1 = (const float*)d_in[19];
  const float* v_b1 = (const float*)d_in[20];
  const float* w_c2 = (const float*)d_in[21];
  const float* g_c2 = (const float*)d_in[22];
  const float* b_c2 = (const float*)d_in[23];
  const float* m_c2 = (const float*)d_in[24];
  const float* v_c2 = (const float*)d_in[25];

  char* ws = (char*)d_ws;
  // arena (bytes)
  ushort* xT     = (ushort*)(ws + 0);            // 32MB  [b][p][256]
  ushort* p1     = (ushort*)(ws + 33554432);     // 16MB  bf16 NCHW
  ushort* p2     = (ushort*)(ws + 50331648);     // 16MB
  ushort* sumT   = (ushort*)(ws + 67108864);     // 16MB  [b][p][128]
  ushort* relu1  = (ushort*)(ws + 83886080);     // 32MB  bf16 NCHW
  ushort* pbn1   = (ushort*)(ws + 33554432);     // 32MB  alias p1+p2 (dead)
  ushort* relu1T = (ushort*)(ws + 0);            // 32MB  alias xT (dead)
  ushort* wR_p1  = (ushort*)(ws + 117440512);
  ushort* wR_p2  = (ushort*)(ws + 118030336);
  ushort* wR_pc  = (ushort*)(ws + 118620160);
  ushort* wR_c1  = (ushort*)(ws + 119209984);
  ushort* wR_c2  = (ushort*)(ws + 119341056);
  float*  tb_p1  = (float*)(ws + 120520704);
  float*  tb_p2  = (float*)(ws + 120521728);
  float*  tb_pc  = (float*)(ws + 120522752);
  float*  tb_c1  = (float*)(ws + 120523776);
  float*  tb_c2  = (float*)(ws + 120524800);
  ushort* zerop  = (ushort*)(ws + 120525824);    // 256B zeros

  hipMemsetAsync(zerop, 0, 256, stream);

  // weight repacks (fold BN scale; emit tb)
  wrepack<<<dim3((128*256*9 + 255)/256), 256, 0, stream>>>(
      w_p1, g_p1, b_p1, m_p1, v_p1, wR_p1, tb_p1, 256, 128, 9);
  wrepack<<<dim3((128*256*9 + 255)/256), 256, 0, stream>>>(
      w_p2, g_p2, b_p2, m_p2, v_p2, wR_p2, tb_p2, 256, 128, 9);
  wrepack<<<dim3((256*128*9 + 255)/256), 256, 0, stream>>>(
      w_pc, g_pb, b_pb, m_pb, v_pb, wR_pc, tb_pc, 128, 256, 9);
  wrepack<<<dim3((256*256*1 + 255)/256), 256, 0, stream>>>(
      w_c1, g_b1, b_b1, m_b1, v_b1, wR_c1, tb_c1, 256, 256, 1);
  wrepack<<<dim3((256*256*9 + 255)/256), 256, 0, stream>>>(
      w_c2, g_c2, b_c2, m_c2, v_c2, wR_c2, tb_c2, 256, 256, 9);

  // x -> xT
  repack_x<<<dim3(NPIX/256, 1, BB), 256, 0, stream>>>(x, xT);

  // p1 = relu(bn(conv3x3(x))), p2 likewise (bf16 NCHW out)
  convgemm<256,128,9,0><<<dim3(HH, 1, BB), 256, 0, stream>>>(
      xT, wR_p1, tb_p1, nullptr, p1, zerop);
  convgemm<256,128,9,0><<<dim3(HH, 1, BB), 256, 0, stream>>>(
      xT, wR_p2, tb_p2, nullptr, p2, zerop);

  // pools (in place)
  scan_h_rev<<<dim3(BB*128), 128, 0, stream>>>(p1);
  scan_w_rev<<<dim3(BB*128*HH/4), 256, 0, stream>>>(p2);

  // sumT = top + left, transposed bf16
  sum_repack<<<dim3(NPIX/256, 1, BB), 256, 0, stream>>>(p1, p2, sumT);

  // pbn1 = bn(conv3x3(sumT)) (no relu), bf16 NCHW (into p1+p2 region)
  convgemm<128,256,9,1><<<dim3(HH, 2, BB), 256, 0, stream>>>(
      sumT, wR_pc, tb_pc, nullptr, pbn1, zerop);

  // relu1 = relu(pbn1 + bn(conv1x1(x))), bf16 NCHW
  convgemm<256,256,1,2><<<dim3(HH, 2, BB), 256, 0, stream>>>(
      xT, wR_c1, tb_c1, pbn1, relu1, zerop);

  // relu1 -> relu1T (into xT region)
  repack_relu1<<<dim3(NPIX/256, 1, BB), 256, 0, stream>>>(relu1, relu1T);

  // out = relu(bn(conv3x3(relu1T))), fp32 NCHW
  convgemm<256,256,9,3><<<dim3(HH, 2, BB), 256, 0, stream>>>(
      relu1T, wR_c2, tb_c2, nullptr, (void*)d_out, zerop);
}